// Round 1
// 1463.948 us; speedup vs baseline: 1.5825x; 1.5825x over previous
//
#include <hip/hip_runtime.h>

// StreamingClusterCompactor: T=32768, H=32, D=128, G=8, hpg=4, M=512
#define T_TOK 32768
#define NH    32
#define DIM   128
#define NG    8
#define HPG   4
#define NM    512
#define TB    32          // tokens per route block
#define NSEG  (NG*NM)     // 4096 segments
#define KSTEP 8           // dims staged per k-slice (16KB per buffer)

// ws layout in 4-byte units:
#define CNT_OFF  0                       // int[4096]  histogram
#define CUR_OFF  4096                    // int[4096]  scatter cursors
#define OFS_OFF  8192                    // int[4096]  segment offsets
#define IDX_OFF  12288                   // int[T*G]   top-1 anchor per (g,t)
#define PERM_OFF (12288 + T_TOK*NG)      // int[T*G]   token permutation (CSR)
#define AT_OFF   (PERM_OFF + T_TOK*NG)   // float[G*D*M] transposed anchors

// ---- async global->LDS 16B helper (wave-uniform LDS base + lane*16) ----
__device__ __forceinline__ void gload_lds16(const float* gp, float* lp)
{
  __builtin_amdgcn_global_load_lds(
      (const __attribute__((address_space(1))) void*)gp,
      (__attribute__((address_space(3))) void*)lp, 16, 0, 0);
}

// ---- Kernel 0: transpose anchors A[g][m][d] -> At[g][d][m] for coalesced staging ----
__global__ __launch_bounds__(256) void transpose_anchors(const float* __restrict__ A,
                                                         float* __restrict__ At)
{
  __shared__ float tile[32][33];
  const int g  = blockIdx.z;
  const int m0 = blockIdx.y * 32;
  const int d0 = blockIdx.x * 32;
  const int tx = threadIdx.x & 31;
  const int ty = threadIdx.x >> 5;   // 0..7
  #pragma unroll
  for (int k = 0; k < 32; k += 8)
    tile[ty + k][tx] = A[((size_t)g * NM + m0 + ty + k) * DIM + d0 + tx];
  __syncthreads();
  #pragma unroll
  for (int k = 0; k < 32; k += 8)
    At[((size_t)g * DIM + d0 + ty + k) * NM + m0 + tx] = tile[tx][ty + k];
}

// ---- Kernel 1: head-mean -> fp32 score GEMM (dbuf gll-staged) -> argmax -> idx + histogram ----
__global__ __launch_bounds__(256, 4) void route(
    const float* __restrict__ K_cold, const float* __restrict__ At,
    int* __restrict__ wsi)
{
  __shared__ float sKg[DIM * 33];                    // Kg^T [d][t], stride 33 (conflict-free)
  __shared__ __align__(16) float sA[2 * KSTEP * NM]; // double-buffered anchor k-slices, linear
  __shared__ int   sBest[TB];

  const int tid  = threadIdx.x;
  const int t0   = blockIdx.x * TB;
  const int g    = blockIdx.y;
  const int tg   = tid >> 5;     // 0..7  (token quad)
  const int ag   = tid & 31;     // 0..31 (anchor lane)
  const int w    = tid >> 6;     // wave id 0..3
  const int lane = tid & 63;

  const float* Atg = At + (size_t)g * DIM * NM;

  // Prologue: async-prefetch k-slice 0 into buffer 0 (overlaps with Phase A)
  #pragma unroll
  for (int i = 0; i < 4; ++i)
    gload_lds16(Atg + (w * 4 + i) * 256 + lane * 4,
                sA + (w * 4 + i) * 256);

  // Phase A: per-group head means of K into LDS (transposed), float4 loads
  {
    const int dq = tid & 31;     // float4 index within D
    const int tk = tid >> 5;     // 0..7
    #pragma unroll
    for (int p = 0; p < 4; ++p) {
      const int t = p * 8 + tk;
      const float* kp = K_cold + ((size_t)(t0 + t) * NH + g * HPG) * DIM + dq * 4;
      const float4 h0 = *(const float4*)(kp);
      const float4 h1 = *(const float4*)(kp + DIM);
      const float4 h2 = *(const float4*)(kp + 2 * DIM);
      const float4 h3 = *(const float4*)(kp + 3 * DIM);
      sKg[(4 * dq + 0) * 33 + t] = 0.25f * (h0.x + h1.x + h2.x + h3.x);
      sKg[(4 * dq + 1) * 33 + t] = 0.25f * (h0.y + h1.y + h2.y + h3.y);
      sKg[(4 * dq + 2) * 33 + t] = 0.25f * (h0.z + h1.z + h2.z + h3.z);
      sKg[(4 * dq + 3) * 33 + t] = 0.25f * (h0.w + h1.w + h2.w + h3.w);
    }
  }

  // Phase B: fp32 scores (scale skipped: argmax-invariant).
  // Thread covers anchors m = q*128 + ag*4 + j  (q=0..3, j=0..3), tokens tg*4+i.
  // Same k-accumulation order as previous kernel -> bit-identical scores.
  float acc[4][16];
  #pragma unroll
  for (int i = 0; i < 4; ++i)
    #pragma unroll
    for (int s = 0; s < 16; ++s) acc[i][s] = 0.f;

  int cur = 0;
  for (int kc = 0; kc < DIM; kc += KSTEP, cur ^= 1) {
    // Drains own in-flight gll (issued a full compute-phase ago) + syncs block.
    __syncthreads();
    // Issue-after-barrier: prefetch next slice into the other buffer.
    if (kc + KSTEP < DIM) {
      const float* gsrc = Atg + (size_t)(kc + KSTEP) * NM;
      float* ldst = sA + (cur ^ 1) * (KSTEP * NM);
      #pragma unroll
      for (int i = 0; i < 4; ++i)
        gload_lds16(gsrc + (w * 4 + i) * 256 + lane * 4,
                    ldst + (w * 4 + i) * 256);
    }
    const float* sa = sA + cur * (KSTEP * NM);
    #pragma unroll
    for (int kk = 0; kk < KSTEP; ++kk) {
      float kv[4];
      #pragma unroll
      for (int i = 0; i < 4; ++i) kv[i] = sKg[(kc + kk) * 33 + tg * 4 + i];
      #pragma unroll
      for (int q = 0; q < 4; ++q) {
        const float4 a = *(const float4*)(sa + kk * NM + q * 128 + ag * 4);
        #pragma unroll
        for (int i = 0; i < 4; ++i) {
          acc[i][q * 4 + 0] = fmaf(kv[i], a.x, acc[i][q * 4 + 0]);
          acc[i][q * 4 + 1] = fmaf(kv[i], a.y, acc[i][q * 4 + 1]);
          acc[i][q * 4 + 2] = fmaf(kv[i], a.z, acc[i][q * 4 + 2]);
          acc[i][q * 4 + 3] = fmaf(kv[i], a.w, acc[i][q * 4 + 3]);
        }
      }
    }
  }

  // Phase C: per-token argmax (lowest index wins ties; in-thread scan is m-increasing)
  #pragma unroll
  for (int i = 0; i < 4; ++i) {
    float bv = acc[i][0];
    int   bm = ag * 4;
    #pragma unroll
    for (int q = 0; q < 4; ++q)
      #pragma unroll
      for (int j = 0; j < 4; ++j) {
        if (q == 0 && j == 0) continue;
        const float v = acc[i][q * 4 + j];
        const int   m = q * 128 + ag * 4 + j;
        if (v > bv) { bv = v; bm = m; }
      }
    for (int off = 16; off >= 1; off >>= 1) {
      const float ov = __shfl_xor(bv, off);
      const int   om = __shfl_xor(bm, off);
      if (ov > bv || (ov == bv && om < bm)) { bv = ov; bm = om; }
    }
    if (ag == 0) sBest[tg * 4 + i] = bm;
  }
  __syncthreads();

  // Phase D: write idx + histogram (int atomics only)
  if (tid < TB) {
    const int m = sBest[tid];
    wsi[IDX_OFF + g * T_TOK + t0 + tid] = m;
    atomicAdd(&wsi[CNT_OFF + g * NM + m], 1);
  }
}

// ---- Kernel 2: exclusive prefix sum over 4096 counts -> offsets + cursors ----
__global__ __launch_bounds__(1024) void scan_kernel(int* __restrict__ wsi)
{
  __shared__ int sdata[1024];
  const int tid = threadIdx.x;
  int c[4], s = 0;
  #pragma unroll
  for (int j = 0; j < 4; ++j) { c[j] = wsi[CNT_OFF + tid * 4 + j]; s += c[j]; }
  sdata[tid] = s;
  __syncthreads();
  for (int off = 1; off < 1024; off <<= 1) {
    const int v = (tid >= off) ? sdata[tid - off] : 0;
    __syncthreads();
    sdata[tid] += v;
    __syncthreads();
  }
  int base = sdata[tid] - s;   // exclusive
  #pragma unroll
  for (int j = 0; j < 4; ++j) {
    wsi[OFS_OFF + tid * 4 + j] = base;
    wsi[CUR_OFF + tid * 4 + j] = base;
    base += c[j];
  }
}

// ---- Kernel 3: build CSR permutation ----
__global__ __launch_bounds__(256) void scatter_kernel(int* __restrict__ wsi)
{
  const int i = blockIdx.x * 256 + threadIdx.x;   // i = g*T + t
  const int g = i >> 15;
  const int t = i & (T_TOK - 1);
  const int m = wsi[IDX_OFF + i];
  const int slot = atomicAdd(&wsi[CUR_OFF + g * NM + m], 1);
  wsi[PERM_OFF + slot] = t;
}

// ---- Kernel 4: per-(g,m) gather-reduce of K and V, normalize, broadcast to heads ----
__global__ __launch_bounds__(256) void reduce_kernel(
    const float* __restrict__ K_cold, const float* __restrict__ V_cold,
    const int* __restrict__ wsi, float* __restrict__ out)
{
  __shared__ float4 sred[256];
  const int gm  = blockIdx.x;
  const int g   = gm >> 9;
  const int m   = gm & (NM - 1);
  const int n   = wsi[CNT_OFF + gm];
  const int o   = wsi[OFS_OFF + gm];
  const int tid = threadIdx.x;
  const int half = tid >> 7;          // 0: K, 1: V
  const int l    = tid & 127;         // element quad e = 4l of the (4h x 128d) token block
  const float* src = half ? V_cold : K_cold;
  const int* perm = wsi + PERM_OFF + o;

  float4 acc = {0.f, 0.f, 0.f, 0.f};
  int j = 0;
  for (; j + 1 < n; j += 2) {
    const int t0 = perm[j], t1 = perm[j + 1];
    const float4 v0 = *(const float4*)(src + ((size_t)t0 * NH + g * HPG) * DIM + l * 4);
    const float4 v1 = *(const float4*)(src + ((size_t)t1 * NH + g * HPG) * DIM + l * 4);
    acc.x += v0.x + v1.x; acc.y += v0.y + v1.y;
    acc.z += v0.z + v1.z; acc.w += v0.w + v1.w;
  }
  if (j < n) {
    const int t = perm[j];
    const float4 v = *(const float4*)(src + ((size_t)t * NH + g * HPG) * DIM + l * 4);
    acc.x += v.x; acc.y += v.y; acc.z += v.z; acc.w += v.w;
  }

  sred[half * 128 + l] = acc;          // l = h*32 + dq (h=l>>5, d=4*(l&31))
  __syncthreads();

  if (tid < 64) {
    const int kv = tid >> 5, dq = tid & 31;
    float4 s = {0.f, 0.f, 0.f, 0.f};
    #pragma unroll
    for (int h = 0; h < 4; ++h) {
      const float4 v = sred[kv * 128 + h * 32 + dq];
      s.x += v.x; s.y += v.y; s.z += v.z; s.w += v.w;
    }
    const float inv = (n > 0) ? (0.25f / (float)n) : 0.f;   // head-mean / count
    s.x *= inv; s.y *= inv; s.z *= inv; s.w *= inv;
    float* ob = out + (size_t)kv * NM * NH * DIM + ((size_t)m * NH + g * HPG) * DIM + dq * 4;
    #pragma unroll
    for (int h = 0; h < 4; ++h) *((float4*)(ob + h * DIM)) = s;
  }
}

extern "C" void kernel_launch(void* const* d_in, const int* in_sizes, int n_in,
                              void* d_out, int out_size, void* d_ws, size_t ws_size,
                              hipStream_t stream)
{
  const float* K = (const float*)d_in[0];
  const float* V = (const float*)d_in[1];
  const float* A = (const float*)d_in[2];
  int*   wsi = (int*)d_ws;
  float* At  = (float*)d_ws + AT_OFF;

  hipMemsetAsync(wsi + CNT_OFF, 0, NSEG * sizeof(int), stream);

  transpose_anchors<<<dim3(DIM / 32, NM / 32, NG), 256, 0, stream>>>(A, At);
  route<<<dim3(T_TOK / TB, NG), 256, 0, stream>>>(K, At, wsi);
  scan_kernel<<<1, 1024, 0, stream>>>(wsi);
  scatter_kernel<<<(T_TOK * NG) / 256, 256, 0, stream>>>(wsi);
  reduce_kernel<<<NSEG, 256, 0, stream>>>(K, V, wsi, (float*)d_out);
}